// Round 1
// baseline (85.058 us; speedup 1.0000x reference)
//
#include <hip/hip_runtime.h>

#define B_DIM 512
#define C_DIM 512
#define BC (B_DIM * C_DIM)

// ---------------------------------------------------------------------------
// Layout constants (see reference):
//  out[L] has NCH[L] contributing l1-chunks, concatenated along channel axis.
//  BASE[L] = cumulative element offset of out[L] in units of BC.
//  chunk index of l1 within out[L] = l1 - FIRST_L1[L].
// ---------------------------------------------------------------------------
constexpr int NCH[6]      = {6, 5, 5, 4, 4, 3};
constexpr int BASE[6]     = {0, 6, 21, 46, 74, 110};   // x BC elements
constexpr int FIRST_L1[6] = {0, 1, 1, 2, 2, 3};

// ws layout: symmetrized-compact cg per l1, ordered (L asc, M asc, pair asc)
// pair p enumerates (a<=b) triangular order: p = a*d - a*(a-1)/2 + (b-a)
// ws_base per l1: cumulative of sizes {1, 54, 375, 1008, 1620, 2376}
//   l1:      0    1     2     3      4      5
static const int WS_BASE_H[6] = {0, 1, 55, 430, 1438, 3058};
// total = 5434 floats = 21736 bytes

struct PrepArgs {
    const float* src[27];
    int dst[27];
    int dim[27];     // d = 2*l1+1
    int twoLp1[27];  // 2*L+1
};

// Symmetrize cg into compact triangular form in ws.
// cgs[M, p(a<=b)] = cg[M,a,b] + cg[M,b,a]  (a<b);  cg[M,a,a] on diagonal.
__global__ void prep_kernel(PrepArgs pa, float* __restrict__ ws) {
    const int j = blockIdx.x;
    const float* __restrict__ cg = pa.src[j];
    const int d = pa.dim[j];
    const int NP = d * (d + 1) / 2;
    const int total = pa.twoLp1[j] * NP;
    for (int e = threadIdx.x; e < total; e += blockDim.x) {
        const int M = e / NP;
        const int p = e - M * NP;
        int na = 0, rem = p;
        while (rem >= d - na) { rem -= d - na; ++na; }
        const int nb = na + rem;
        float v = cg[(M * d + na) * d + nb];
        if (na != nb) v += cg[(M * d + nb) * d + na];
        ws[pa.dst[j] + e] = v;
    }
}

template <int L1>
__device__ __forceinline__ void tp_body(const float* __restrict__ x,
                                        const float* __restrict__ cgs,
                                        float* __restrict__ out, int blk) {
    constexpr int d    = 2 * L1 + 1;
    constexpr int NP   = d * (d + 1) / 2;
    constexpr int Lmax = (2 * L1 < 5) ? 2 * L1 : 5;

    const int t = blk * 256 + (int)threadIdx.x;   // (b,i) flat index
    const int b = t >> 9;                          // / C_DIM
    const int i = t & (C_DIM - 1);

    // load this (b,i)'s x vector (contiguous d floats)
    float xv[d];
#pragma unroll
    for (int m = 0; m < d; ++m) xv[m] = x[t * d + m];

    // symmetric outer product, triangular
    float o[NP];
#pragma unroll
    for (int a = 0; a < d; ++a) {
#pragma unroll
        for (int bb = a; bb < d; ++bb) {
            o[a * d - a * (a - 1) / 2 + (bb - a)] = xv[a] * xv[bb];
        }
    }

    // contributions to each output degree L
#pragma unroll
    for (int L = 0; L <= Lmax; ++L) {
        const int twoLp1 = 2 * L + 1;
        const int chunk  = L1 - FIRST_L1[L];
        const int obase  = BASE[L] * BC + ((b * NCH[L] + chunk) * C_DIM + i) * twoLp1;
        const int co0    = L * L * NP;  // cumulative (2L'+1) for L'<L is L^2
#pragma unroll
        for (int M = 0; M < twoLp1; ++M) {
            float acc = 0.0f;
#pragma unroll
            for (int p = 0; p < NP; ++p)
                acc = fmaf(cgs[co0 + M * NP + p], o[p], acc);
            out[obase + M] = acc;
        }
    }
}

// One fused launch; parts ordered by descending work so heavy blocks start first.
__global__ __launch_bounds__(256) void tp_all(
    const float* __restrict__ x0, const float* __restrict__ x1,
    const float* __restrict__ x2, const float* __restrict__ x3,
    const float* __restrict__ x4, const float* __restrict__ x5,
    const float* __restrict__ ws, float* __restrict__ out) {
    const int part = blockIdx.x >> 10;   // 1024 blocks per part
    const int blk  = blockIdx.x & 1023;
    switch (part) {
        case 0:  tp_body<5>(x5, ws + 3058, out, blk); break;
        case 1:  tp_body<4>(x4, ws + 1438, out, blk); break;
        case 2:  tp_body<3>(x3, ws + 430,  out, blk); break;
        case 3:  tp_body<2>(x2, ws + 55,   out, blk); break;
        case 4:  tp_body<1>(x1, ws + 1,    out, blk); break;
        default: tp_body<0>(x0, ws + 0,    out, blk); break;
    }
}

extern "C" void kernel_launch(void* const* d_in, const int* in_sizes, int n_in,
                              void* d_out, int out_size, void* d_ws, size_t ws_size,
                              hipStream_t stream) {
    (void)in_sizes; (void)n_in; (void)out_size; (void)ws_size;

    PrepArgs pa;
    int j = 0;
    for (int l1 = 0; l1 <= 5; ++l1) {
        const int d = 2 * l1 + 1;
        const int NP = d * (d + 1) / 2;
        const int Lmax = (2 * l1 < 5) ? 2 * l1 : 5;
        for (int L = 0; L <= Lmax; ++L) {
            pa.src[j]    = (const float*)d_in[6 + j];
            pa.dst[j]    = WS_BASE_H[l1] + L * L * NP;
            pa.dim[j]    = d;
            pa.twoLp1[j] = 2 * L + 1;
            ++j;
        }
    }

    float* ws = (float*)d_ws;
    hipLaunchKernelGGL(prep_kernel, dim3(27), dim3(256), 0, stream, pa, ws);
    hipLaunchKernelGGL(tp_all, dim3(6 * 1024), dim3(256), 0, stream,
                       (const float*)d_in[0], (const float*)d_in[1],
                       (const float*)d_in[2], (const float*)d_in[3],
                       (const float*)d_in[4], (const float*)d_in[5],
                       (const float*)ws, (float*)d_out);
}